// Round 3
// baseline (634.278 us; speedup 1.0000x reference)
//
#include <hip/hip_runtime.h>

// ---------------------------------------------------------------------------
// GCN stack, one workgroup (512 thr) per batch element, 2 WG/CU.
//   B=4096 N=128 U=128 H=6
// Round-3 structure: FRAGMENT-MAJOR LDS layouts.
//   sX holds X with rows=nodes, k=units; sY holds Y^T with rows=units,
//   k=nodes; both stored in MFMA A-fragment order:
//     addr(r,k) = (r>>4)*2048 + (k>>3)*128 + (r&15)*8 + (k&7)   [shorts]
//   => every GEMM ds_read is base + compile-time immediate (rt*4096+ks*1024
//      bytes), zero per-read VALU; banks provably balanced (8 dwords/bank
//      per b128 read = data minimum; 4/bank per b64 epilogue write).
//   GEMM orientations make each epilogue's 4 consecutive C-rows the k-dim
//   of the consumer layout -> all LDS writes are contiguous 8 B, no scatter:
//     GEMM1: D=Y      (A = X rows=nodes from sX, B = W_h^T global L1-hot)
//     GEMM2: D=X'^T   (A = Y^T rows=units from sY, B = adj^T in REGISTERS)
//   adjB[2][4] (32 VGPR) held for the whole kernel, as in round 2.
// ---------------------------------------------------------------------------

typedef __bf16  bf16x8 __attribute__((ext_vector_type(8)));
typedef __bf16  bf16x4 __attribute__((ext_vector_type(4)));
typedef float   f32x4  __attribute__((ext_vector_type(4)));
typedef float   f32x8  __attribute__((ext_vector_type(8)));

// fragment-major index, K=128 buffers (sX, sY)
#define AIDX(r, k)  ((((r) >> 4) << 11) + (((k) >> 3) << 7) + (((r) & 15) << 3) + ((k) & 7))
// fragment-major index, K=32 staging buffer (X0 in sY region)
#define BIDX32(r, k) ((((r) >> 4) << 9) + (((k) >> 3) << 7) + (((r) & 15) << 3) + ((k) & 7))

__device__ __forceinline__ f32x4 mfma16(bf16x8 a, bf16x8 b, f32x4 c) {
    return __builtin_amdgcn_mfma_f32_16x16x32_bf16(a, b, c, 0, 0, 0);
}
__device__ __forceinline__ bf16x8 cvt8(float4 lo, float4 hi) {
    f32x8 f; f[0]=lo.x; f[1]=lo.y; f[2]=lo.z; f[3]=lo.w;
             f[4]=hi.x; f[5]=hi.y; f[6]=hi.z; f[7]=hi.w;
    return __builtin_convertvector(f, bf16x8);   // RNE
}
__device__ __forceinline__ bf16x4 cvt4(f32x4 v) {
    return __builtin_convertvector(v, bf16x4);
}

// ---- prep: transpose weights to bf16 in workspace -------------------------
// wt_in : [128 out][32 in] (in 16..31 zero)   8 KB
// wt_h  : [6][128 out][128 in]              192 KB
__global__ void gcn_prep(const float* __restrict__ W_in,
                         const float* __restrict__ W_h,
                         __bf16* __restrict__ wt_in,
                         __bf16* __restrict__ wt_h) {
    int idx = blockIdx.x * 256 + threadIdx.x;
    if (idx < 4096) {
        int o = idx >> 5, i = idx & 31;
        wt_in[idx] = (i < 16) ? (__bf16)W_in[i * 128 + o] : (__bf16)0.f;
    } else {
        int j = idx - 4096;
        if (j < 98304) {
            int l = j >> 14, r = j & 16383, o = r >> 7, i = r & 127;
            wt_h[j] = (__bf16)W_h[l * 16384 + i * 128 + o];
        }
    }
}

__global__ __launch_bounds__(512, 4) void gcn_main(
    const int* __restrict__ pdg, const float* __restrict__ feat,
    const float* __restrict__ adj, const float* __restrict__ mask,
    const float* __restrict__ emb, const float* __restrict__ b_in,
    const float* __restrict__ b_h, const float* __restrict__ W_out,
    const float* __restrict__ b_out,
    const __bf16* __restrict__ wt_in, const __bf16* __restrict__ wt_h,
    float* __restrict__ out) {

    __shared__ __attribute__((aligned(16))) __bf16 sX[128 * 128];  // 32 KB
    __shared__ __attribute__((aligned(16))) __bf16 sY[128 * 128];  // 32 KB
    __shared__ float red[16];

    const int b    = blockIdx.x;
    const int tid  = threadIdx.x;
    const int lane = tid & 63;
    const int wave = tid >> 6;
    const int q    = lane >> 4;   // k-chunk quad / C row-quad
    const int c    = lane & 15;   // fragment row/col within 16
    const int wm   = wave >> 2;   // M strip: 64*wm   (2 groups)
    const int wn   = wave & 3;    // N strip: 32*wn   (4 groups)

    // ---- adj^T B-fragments -> registers, held for the whole kernel --------
    // adjB[ct][ks]: lane(q,c) holds adj[n = wn*32+ct*16+c][k = ks*32+q*8 ..+7]
    bf16x8 adjB[2][4];
    {
        const float* ap = adj + (size_t)b * 16384;
        #pragma unroll
        for (int ct = 0; ct < 2; ++ct) {
            const float* rp = ap + (wn * 32 + ct * 16 + c) * 128 + q * 8;
            #pragma unroll
            for (int ks = 0; ks < 4; ++ks) {
                const float4* p = (const float4*)(rp + ks * 32);
                adjB[ct][ks] = cvt8(p[0], p[1]);
            }
        }
    }

    // ---- stage X0 = [feat | emb | 0] frag-major (K=32) into sY region -----
    {
        int node = tid >> 2, part = tid & 3;
        bf16x8 v;
        if (part == 0) {
            const float4* f = (const float4*)(feat + ((size_t)b * 128 + node) * 8);
            v = cvt8(f[0], f[1]);
        } else if (part == 1) {
            const float4* e = (const float4*)(emb + pdg[b * 128 + node] * 8);
            v = cvt8(e[0], e[1]);
        } else {
            #pragma unroll
            for (int i = 0; i < 8; ++i) v[i] = (__bf16)0.f;
        }
        *(bf16x8*)&sY[BIDX32(node, part * 8)] = v;
    }
    __syncthreads();

    // ---- input layer: D = X1^T (M=units), A = wt_in, B = X0; -> sX --------
    {
        f32x4 acc[4][2];
        #pragma unroll
        for (int rt = 0; rt < 4; ++rt)
            #pragma unroll
            for (int ct = 0; ct < 2; ++ct) acc[rt][ct] = (f32x4){0.f,0.f,0.f,0.f};
        bf16x8 bx0 = *(const bf16x8*)&sY[BIDX32(wn * 32 +  0 + c, q * 8)];
        bf16x8 bx1 = *(const bf16x8*)&sY[BIDX32(wn * 32 + 16 + c, q * 8)];
        #pragma unroll
        for (int rt = 0; rt < 4; ++rt) {
            bf16x8 aw = *(const bf16x8*)&wt_in[(wm * 64 + rt * 16 + c) * 32 + q * 8];
            acc[rt][0] = mfma16(aw, bx0, acc[rt][0]);
            acc[rt][1] = mfma16(aw, bx1, acc[rt][1]);
        }
        // lane holds X1^T[u0..u0+3][node] = X1[node][4 consecutive units]
        #pragma unroll
        for (int rt = 0; rt < 4; ++rt) {
            int u0 = wm * 64 + rt * 16 + q * 4;
            float4 bi = *(const float4*)&b_in[u0];
            #pragma unroll
            for (int ct = 0; ct < 2; ++ct) {
                int node = wn * 32 + ct * 16 + c;
                f32x4 v;
                v[0] = acc[rt][ct][0] + bi.x; v[1] = acc[rt][ct][1] + bi.y;
                v[2] = acc[rt][ct][2] + bi.z; v[3] = acc[rt][ct][3] + bi.w;
                *(bf16x4*)&sX[AIDX(node, u0)] = cvt4(v);
            }
        }
    }
    __syncthreads();

    // ---- 6 hidden layers ----
    #pragma unroll 1
    for (int l = 0; l < 6; ++l) {
        const __bf16* wt = wt_h + l * 16384;   // [out][in] bf16 (= W^T)
        // GEMM1: D = Y = X@W + b, relu.  A = sX (rows=nodes), B = wt (global)
        {
            f32x4 acc[4][2];
            #pragma unroll
            for (int rt = 0; rt < 4; ++rt)
                #pragma unroll
                for (int ct = 0; ct < 2; ++ct) acc[rt][ct] = (f32x4){0.f,0.f,0.f,0.f};
            #pragma unroll
            for (int ks = 0; ks < 4; ++ks) {
                bf16x8 w0 = *(const bf16x8*)&wt[(wn * 32 +  0 + c) * 128 + ks * 32 + q * 8];
                bf16x8 w1 = *(const bf16x8*)&wt[(wn * 32 + 16 + c) * 128 + ks * 32 + q * 8];
                #pragma unroll
                for (int rt = 0; rt < 4; ++rt) {
                    bf16x8 a = *(const bf16x8*)&sX[AIDX(wm * 64 + rt * 16 + c, ks * 32 + q * 8)];
                    acc[rt][0] = mfma16(a, w0, acc[rt][0]);
                    acc[rt][1] = mfma16(a, w1, acc[rt][1]);
                }
            }
            // lane holds Y[n0..n0+3][unit] -> sY frag-major (rows=units, k=nodes)
            #pragma unroll
            for (int ct = 0; ct < 2; ++ct) {
                int u = wn * 32 + ct * 16 + c;
                float bias = b_h[l * 128 + u];
                #pragma unroll
                for (int rt = 0; rt < 4; ++rt) {
                    int n0 = wm * 64 + rt * 16 + q * 4;
                    f32x4 v;
                    #pragma unroll
                    for (int j = 0; j < 4; ++j) v[j] = fmaxf(acc[rt][ct][j] + bias, 0.f);
                    *(bf16x4*)&sY[AIDX(u, n0)] = cvt4(v);
                }
            }
        }
        __syncthreads();
        // GEMM2: D = X'^T = Y^T @ adj^T.  A = sY (rows=units), B = adjB regs
        {
            f32x4 acc[4][2];
            #pragma unroll
            for (int rt = 0; rt < 4; ++rt)
                #pragma unroll
                for (int ct = 0; ct < 2; ++ct) acc[rt][ct] = (f32x4){0.f,0.f,0.f,0.f};
            #pragma unroll
            for (int ks = 0; ks < 4; ++ks) {
                #pragma unroll
                for (int rt = 0; rt < 4; ++rt) {
                    bf16x8 a = *(const bf16x8*)&sY[AIDX(wm * 64 + rt * 16 + c, ks * 32 + q * 8)];
                    acc[rt][0] = mfma16(a, adjB[0][ks], acc[rt][0]);
                    acc[rt][1] = mfma16(a, adjB[1][ks], acc[rt][1]);
                }
            }
            // lane holds X'^T[u0..u0+3][node] = X'[node][4 consecutive units]
            #pragma unroll
            for (int ct = 0; ct < 2; ++ct) {
                int node = wn * 32 + ct * 16 + c;
                #pragma unroll
                for (int rt = 0; rt < 4; ++rt) {
                    int u0 = wm * 64 + rt * 16 + q * 4;
                    *(bf16x4*)&sX[AIDX(node, u0)] = cvt4(acc[rt][ct]);
                }
            }
        }
        __syncthreads();
    }

    // ---- epilogue: masked mean pool + W_out dot ----
    {
        int node = tid >> 2, seg = tid & 3;
        float part = 0.f;
        #pragma unroll
        for (int t = 0; t < 4; ++t) {
            bf16x8 v = *(const bf16x8*)&sX[AIDX(node, seg * 32 + t * 8)];
            const float* wo = W_out + seg * 32 + t * 8;
            #pragma unroll
            for (int j = 0; j < 8; ++j) part += (float)v[j] * wo[j];
        }
        float mv = mask[b * 128 + node];
        part *= mv;
        float msum = (seg == 0) ? mv : 0.f;
        #pragma unroll
        for (int off = 32; off > 0; off >>= 1) {
            part += __shfl_down(part, off);
            msum += __shfl_down(msum, off);
        }
        if (lane == 0) { red[wave] = part; red[8 + wave] = msum; }
        __syncthreads();
        if (tid == 0) {
            float s = 0.f, ms = 0.f;
            #pragma unroll
            for (int i = 0; i < 8; ++i) { s += red[i]; ms += red[8 + i]; }
            out[b] = s / fmaxf(ms, 1.f) + b_out[0];
        }
    }
}

extern "C" void kernel_launch(void* const* d_in, const int* in_sizes, int n_in,
                              void* d_out, int out_size, void* d_ws, size_t ws_size,
                              hipStream_t stream) {
    const int*   pdg   = (const int*)d_in[0];
    const float* feat  = (const float*)d_in[1];
    const float* adj   = (const float*)d_in[2];
    const float* mask  = (const float*)d_in[3];
    const float* emb   = (const float*)d_in[4];
    const float* W_in  = (const float*)d_in[5];
    const float* b_in  = (const float*)d_in[6];
    const float* W_h   = (const float*)d_in[7];
    const float* b_h   = (const float*)d_in[8];
    const float* W_out = (const float*)d_in[9];
    const float* b_out = (const float*)d_in[10];

    __bf16* wt_in = (__bf16*)d_ws;          // 128*32 bf16
    __bf16* wt_h  = wt_in + 4096;           // 6*128*128 bf16

    gcn_prep<<<400, 256, 0, stream>>>(W_in, W_h, wt_in, wt_h);
    gcn_main<<<4096, 512, 0, stream>>>(pdg, feat, adj, mask, emb, b_in, b_h,
                                       W_out, b_out, wt_in, wt_h, (float*)d_out);
}

// Round 4
// 621.718 us; speedup vs baseline: 1.0202x; 1.0202x over previous
//
#include <hip/hip_runtime.h>

// ---------------------------------------------------------------------------
// GCN stack, one workgroup (512 thr) per batch element, 2 WG/CU.
//   B=4096 N=128 U=128 H=6
// Round-4 structure (on top of round-3 fragment-major LDS):
//  - wt_h B-fragments SOFTWARE-PIPELINED into registers: layer l+1's 8 b128
//    frags are issued at the start of layer l's GEMM2 (LDS-only phase) into
//    the idle half of a double buffer (wfA/wfB). G1 phases contain zero
//    global loads -> no vmcnt in their barrier drains, no L2 latency in the
//    ds_read->MFMA chain. Next-layer biases prefetched the same way.
//  - bias folded into MFMA acc init (D = A*B + C, C = bias broadcast).
//  - 6-layer loop fully unrolled: register double-buffer with no copies,
//    all LDS offsets immediate.
//  - adjB[2][4] (32 VGPR) held in registers for the whole kernel (round 2).
// LDS: sX + sY 32 KB each, frag-major:
//     AIDX(r,k) = (r>>4)*2048 + (k>>3)*128 + (r&15)*8 + (k&7)
// GEMM1: D=Y      (A = sX rows=nodes, B = wf regs)        -> sY (Y^T)
// GEMM2: D=X'^T   (A = sY rows=units, B = adjB regs)      -> sX (X')
// ---------------------------------------------------------------------------

typedef __bf16  bf16x8 __attribute__((ext_vector_type(8)));
typedef __bf16  bf16x4 __attribute__((ext_vector_type(4)));
typedef float   f32x4  __attribute__((ext_vector_type(4)));
typedef float   f32x8  __attribute__((ext_vector_type(8)));

#define AIDX(r, k)   ((((r) >> 4) << 11) + (((k) >> 3) << 7) + (((r) & 15) << 3) + ((k) & 7))
#define BIDX32(r, k) ((((r) >> 4) << 9) + (((k) >> 3) << 7) + (((r) & 15) << 3) + ((k) & 7))

__device__ __forceinline__ f32x4 mfma16(bf16x8 a, bf16x8 b, f32x4 c) {
    return __builtin_amdgcn_mfma_f32_16x16x32_bf16(a, b, c, 0, 0, 0);
}
__device__ __forceinline__ bf16x8 cvt8(float4 lo, float4 hi) {
    f32x8 f; f[0]=lo.x; f[1]=lo.y; f[2]=lo.z; f[3]=lo.w;
             f[4]=hi.x; f[5]=hi.y; f[6]=hi.z; f[7]=hi.w;
    return __builtin_convertvector(f, bf16x8);   // RNE
}
__device__ __forceinline__ bf16x4 cvt4(f32x4 v) {
    return __builtin_convertvector(v, bf16x4);
}

// ---- prep: transpose weights to bf16 in workspace -------------------------
__global__ void gcn_prep(const float* __restrict__ W_in,
                         const float* __restrict__ W_h,
                         __bf16* __restrict__ wt_in,
                         __bf16* __restrict__ wt_h) {
    int idx = blockIdx.x * 256 + threadIdx.x;
    if (idx < 4096) {
        int o = idx >> 5, i = idx & 31;
        wt_in[idx] = (i < 16) ? (__bf16)W_in[i * 128 + o] : (__bf16)0.f;
    } else {
        int j = idx - 4096;
        if (j < 98304) {
            int l = j >> 14, r = j & 16383, o = r >> 7, i = r & 127;
            wt_h[j] = (__bf16)W_h[l * 16384 + i * 128 + o];
        }
    }
}

// G1: Y = relu(X @ W_h[l] + b); A from sX, B = WF regs; writes Y^T -> sY
#define G1_PHASE(WF, B0, B1)                                                 \
    {                                                                        \
        f32x4 acc[4][2];                                                     \
        _Pragma("unroll") for (int rt = 0; rt < 4; ++rt) {                   \
            acc[rt][0] = (f32x4){B0, B0, B0, B0};                            \
            acc[rt][1] = (f32x4){B1, B1, B1, B1};                            \
        }                                                                    \
        _Pragma("unroll") for (int ks = 0; ks < 4; ++ks) {                   \
            _Pragma("unroll") for (int rt = 0; rt < 4; ++rt) {               \
                bf16x8 a = *(const bf16x8*)&sX[AIDX(wm*64 + rt*16 + c, ks*32 + q*8)]; \
                acc[rt][0] = mfma16(a, WF[0][ks], acc[rt][0]);               \
                acc[rt][1] = mfma16(a, WF[1][ks], acc[rt][1]);               \
            }                                                                \
        }                                                                    \
        _Pragma("unroll") for (int ct = 0; ct < 2; ++ct) {                   \
            int u = wn*32 + ct*16 + c;                                       \
            _Pragma("unroll") for (int rt = 0; rt < 4; ++rt) {               \
                int n0 = wm*64 + rt*16 + q*4;                                \
                f32x4 v;                                                     \
                _Pragma("unroll") for (int j = 0; j < 4; ++j)                \
                    v[j] = fmaxf(acc[rt][ct][j], 0.f);                       \
                *(bf16x4*)&sY[AIDX(u, n0)] = cvt4(v);                        \
            }                                                                \
        }                                                                    \
    }

// G2: X'^T = Y^T @ adj^T; A from sY, B = adjB regs; writes X' -> sX.
// DO_PRE: issue next layer's wt frags + biases into WFN/NB0/NB1 first.
#define G2_PHASE(WFN, NB0, NB1, NEXTL, DO_PRE)                               \
    {                                                                        \
        if (DO_PRE) {                                                        \
            const __bf16* wtn = wt_h + (NEXTL) * 16384;                      \
            _Pragma("unroll") for (int ct = 0; ct < 2; ++ct)                 \
                _Pragma("unroll") for (int ks = 0; ks < 4; ++ks)             \
                    WFN[ct][ks] = *(const bf16x8*)&wtn[(wn*32 + ct*16 + c)*128 + ks*32 + q*8]; \
            NB0 = b_h[(NEXTL)*128 + wn*32 + c];                              \
            NB1 = b_h[(NEXTL)*128 + wn*32 + 16 + c];                         \
        }                                                                    \
        f32x4 acc[4][2];                                                     \
        _Pragma("unroll") for (int rt = 0; rt < 4; ++rt) {                   \
            acc[rt][0] = (f32x4){0.f, 0.f, 0.f, 0.f};                        \
            acc[rt][1] = (f32x4){0.f, 0.f, 0.f, 0.f};                        \
        }                                                                    \
        _Pragma("unroll") for (int ks = 0; ks < 4; ++ks) {                   \
            _Pragma("unroll") for (int rt = 0; rt < 4; ++rt) {               \
                bf16x8 a = *(const bf16x8*)&sY[AIDX(wm*64 + rt*16 + c, ks*32 + q*8)]; \
                acc[rt][0] = mfma16(a, adjB[0][ks], acc[rt][0]);             \
                acc[rt][1] = mfma16(a, adjB[1][ks], acc[rt][1]);             \
            }                                                                \
        }                                                                    \
        _Pragma("unroll") for (int ct = 0; ct < 2; ++ct) {                   \
            int node = wn*32 + ct*16 + c;                                    \
            _Pragma("unroll") for (int rt = 0; rt < 4; ++rt) {               \
                int u0 = wm*64 + rt*16 + q*4;                                \
                *(bf16x4*)&sX[AIDX(node, u0)] = cvt4(acc[rt][ct]);           \
            }                                                                \
        }                                                                    \
    }

__global__ __launch_bounds__(512, 4) void gcn_main(
    const int* __restrict__ pdg, const float* __restrict__ feat,
    const float* __restrict__ adj, const float* __restrict__ mask,
    const float* __restrict__ emb, const float* __restrict__ b_in,
    const float* __restrict__ b_h, const float* __restrict__ W_out,
    const float* __restrict__ b_out,
    const __bf16* __restrict__ wt_in, const __bf16* __restrict__ wt_h,
    float* __restrict__ out) {

    __shared__ __attribute__((aligned(16))) __bf16 sX[128 * 128];  // 32 KB
    __shared__ __attribute__((aligned(16))) __bf16 sY[128 * 128];  // 32 KB
    __shared__ float red[16];

    const int b    = blockIdx.x;
    const int tid  = threadIdx.x;
    const int lane = tid & 63;
    const int wave = tid >> 6;
    const int q    = lane >> 4;   // k-chunk quad / C row-quad
    const int c    = lane & 15;   // fragment row/col within 16
    const int wm   = wave >> 2;   // M strip: 64*wm   (2 groups)
    const int wn   = wave & 3;    // N strip: 32*wn   (4 groups)

    // ---- adj^T B-fragments -> registers, held for the whole kernel --------
    bf16x8 adjB[2][4];
    {
        const float* ap = adj + (size_t)b * 16384;
        #pragma unroll
        for (int ct = 0; ct < 2; ++ct) {
            const float* rp = ap + (wn * 32 + ct * 16 + c) * 128 + q * 8;
            #pragma unroll
            for (int ks = 0; ks < 4; ++ks) {
                const float4* p = (const float4*)(rp + ks * 32);
                adjB[ct][ks] = cvt8(p[0], p[1]);
            }
        }
    }

    // ---- wt double buffer: preload layer 0 frags + bias -------------------
    bf16x8 wfA[2][4], wfB[2][4];
    float b0A, b1A, b0B, b1B;
    {
        #pragma unroll
        for (int ct = 0; ct < 2; ++ct)
            #pragma unroll
            for (int ks = 0; ks < 4; ++ks)
                wfA[ct][ks] = *(const bf16x8*)&wt_h[(wn*32 + ct*16 + c)*128 + ks*32 + q*8];
        b0A = b_h[wn*32 + c];
        b1A = b_h[wn*32 + 16 + c];
    }

    // ---- stage X0 = [feat | emb | 0] frag-major (K=32) into sY region -----
    {
        int node = tid >> 2, part = tid & 3;
        bf16x8 v;
        if (part == 0) {
            const float4* f = (const float4*)(feat + ((size_t)b * 128 + node) * 8);
            v = cvt8(f[0], f[1]);
        } else if (part == 1) {
            const float4* e = (const float4*)(emb + pdg[b * 128 + node] * 8);
            v = cvt8(e[0], e[1]);
        } else {
            #pragma unroll
            for (int i = 0; i < 8; ++i) v[i] = (__bf16)0.f;
        }
        *(bf16x8*)&sY[BIDX32(node, part * 8)] = v;
    }
    __syncthreads();

    // ---- input layer: D = X1^T (M=units), A = wt_in, B = X0; -> sX --------
    {
        f32x4 acc[4][2];
        #pragma unroll
        for (int rt = 0; rt < 4; ++rt) {
            int u0 = wm * 64 + rt * 16 + q * 4;
            float4 bi = *(const float4*)&b_in[u0];
            acc[rt][0] = (f32x4){bi.x, bi.y, bi.z, bi.w};
            acc[rt][1] = acc[rt][0];
        }
        bf16x8 bx0 = *(const bf16x8*)&sY[BIDX32(wn * 32 +  0 + c, q * 8)];
        bf16x8 bx1 = *(const bf16x8*)&sY[BIDX32(wn * 32 + 16 + c, q * 8)];
        #pragma unroll
        for (int rt = 0; rt < 4; ++rt) {
            bf16x8 aw = *(const bf16x8*)&wt_in[(wm * 64 + rt * 16 + c) * 32 + q * 8];
            acc[rt][0] = mfma16(aw, bx0, acc[rt][0]);
            acc[rt][1] = mfma16(aw, bx1, acc[rt][1]);
        }
        // lane holds X1^T[u0..u0+3][node] = X1[node][4 consecutive units]
        #pragma unroll
        for (int rt = 0; rt < 4; ++rt) {
            int u0 = wm * 64 + rt * 16 + q * 4;
            #pragma unroll
            for (int ct = 0; ct < 2; ++ct) {
                int node = wn * 32 + ct * 16 + c;
                *(bf16x4*)&sX[AIDX(node, u0)] = cvt4(acc[rt][ct]);
            }
        }
    }
    __syncthreads();

    // ---- 6 hidden layers, fully unrolled, wf double-buffered --------------
    G1_PHASE(wfA, b0A, b1A); __syncthreads();
    G2_PHASE(wfB, b0B, b1B, 1, 1);  __syncthreads();
    G1_PHASE(wfB, b0B, b1B); __syncthreads();
    G2_PHASE(wfA, b0A, b1A, 2, 1);  __syncthreads();
    G1_PHASE(wfA, b0A, b1A); __syncthreads();
    G2_PHASE(wfB, b0B, b1B, 3, 1);  __syncthreads();
    G1_PHASE(wfB, b0B, b1B); __syncthreads();
    G2_PHASE(wfA, b0A, b1A, 4, 1);  __syncthreads();
    G1_PHASE(wfA, b0A, b1A); __syncthreads();
    G2_PHASE(wfB, b0B, b1B, 5, 1);  __syncthreads();
    G1_PHASE(wfB, b0B, b1B); __syncthreads();
    G2_PHASE(wfA, b0A, b1A, 0, 0);  __syncthreads();

    // ---- epilogue: masked mean pool + W_out dot ----
    {
        int node = tid >> 2, seg = tid & 3;
        float part = 0.f;
        #pragma unroll
        for (int t = 0; t < 4; ++t) {
            bf16x8 v = *(const bf16x8*)&sX[AIDX(node, seg * 32 + t * 8)];
            const float* wo = W_out + seg * 32 + t * 8;
            #pragma unroll
            for (int j = 0; j < 8; ++j) part += (float)v[j] * wo[j];
        }
        float mv = mask[b * 128 + node];
        part *= mv;
        float msum = (seg == 0) ? mv : 0.f;
        #pragma unroll
        for (int off = 32; off > 0; off >>= 1) {
            part += __shfl_down(part, off);
            msum += __shfl_down(msum, off);
        }
        if (lane == 0) { red[wave] = part; red[8 + wave] = msum; }
        __syncthreads();
        if (tid == 0) {
            float s = 0.f, ms = 0.f;
            #pragma unroll
            for (int i = 0; i < 8; ++i) { s += red[i]; ms += red[8 + i]; }
            out[b] = s / fmaxf(ms, 1.f) + b_out[0];
        }
    }
}

extern "C" void kernel_launch(void* const* d_in, const int* in_sizes, int n_in,
                              void* d_out, int out_size, void* d_ws, size_t ws_size,
                              hipStream_t stream) {
    const int*   pdg   = (const int*)d_in[0];
    const float* feat  = (const float*)d_in[1];
    const float* adj   = (const float*)d_in[2];
    const float* mask  = (const float*)d_in[3];
    const float* emb   = (const float*)d_in[4];
    const float* W_in  = (const float*)d_in[5];
    const float* b_in  = (const float*)d_in[6];
    const float* W_h   = (const float*)d_in[7];
    const float* b_h   = (const float*)d_in[8];
    const float* W_out = (const float*)d_in[9];
    const float* b_out = (const float*)d_in[10];

    __bf16* wt_in = (__bf16*)d_ws;          // 128*32 bf16
    __bf16* wt_h  = wt_in + 4096;           // 6*128*128 bf16

    gcn_prep<<<400, 256, 0, stream>>>(W_in, W_h, wt_in, wt_h);
    gcn_main<<<4096, 512, 0, stream>>>(pdg, feat, adj, mask, emb, b_in, b_h,
                                       W_out, b_out, wt_in, wt_h, (float*)d_out);
}